// Round 6
// baseline (112.354 us; speedup 1.0000x reference)
//
#include <hip/hip_runtime.h>
#include <math.h>

#define BATCH 32
#define NP 128
#define NG 64

__device__ __forceinline__ unsigned umin32(unsigned a, unsigned b) { return a < b ? a : b; }

// min all-reduce over each 16-lane row, pure DPP
__device__ __forceinline__ unsigned dpp_min16(unsigned x) {
  unsigned t;
  t = (unsigned)__builtin_amdgcn_update_dpp((int)x, (int)x, 0xB1, 0xF, 0xF, false);  // quad_perm xor1
  x = umin32(x, t);
  t = (unsigned)__builtin_amdgcn_update_dpp((int)x, (int)x, 0x4E, 0xF, 0xF, false);  // quad_perm xor2
  x = umin32(x, t);
  t = (unsigned)__builtin_amdgcn_update_dpp((int)x, (int)x, 0x124, 0xF, 0xF, false); // row_ror:4
  x = umin32(x, t);
  t = (unsigned)__builtin_amdgcn_update_dpp((int)x, (int)x, 0x128, 0xF, 0xF, false); // row_ror:8
  x = umin32(x, t);
  return x;
}

// full-wave64 min reduce -> uniform scalar
__device__ __forceinline__ unsigned wave_min64(unsigned x) {
  x = dpp_min16(x);
  unsigned t;
  t = (unsigned)__builtin_amdgcn_update_dpp((int)x, (int)x, 0x142, 0xF, 0xF, false); // row_bcast15
  x = umin32(x, t);
  t = (unsigned)__builtin_amdgcn_update_dpp((int)x, (int)x, 0x143, 0xF, 0xF, false); // row_bcast31
  x = umin32(x, t);
  return (unsigned)__builtin_amdgcn_readlane((int)x, 63);
}

__device__ __forceinline__ float readlane_f(float v, int l) {
  return __uint_as_float((unsigned)__builtin_amdgcn_readlane((int)__float_as_uint(v), l));
}

// Shared distance formula: identical codegen (explicit fmaf) in build and SAP
// phases => bit-identical costs => exact dual feasibility across phases.
__device__ __forceinline__ float dist3(float px, float py, float pz,
                                       float gx, float gy, float gz) {
  const float dx = px - gx, dy = py - gy, dz = pz - gz;
  return sqrtf(__builtin_fmaf(dx, dx, __builtin_fmaf(dy, dy, dz * dz)));
}

// One wave64 per sample. Exact LSA: row-reduction + greedy claim init, then
// JV shortest augmenting path for the ~14 free rows. NO cost matrix: costs
// are recomputed in-register during the scan (coords held in VGPRs; row
// coords fetched with 3 readlanes) — removes the 120-cy dependent LDS read
// from the serial recurrence. Packed u32 keys (truncated f32 | 7-bit col) +
// 6-step DPP wave argmin; deferred dual updates via running delta D.
__global__ __launch_bounds__(64) void mtl_kernel(
    const float* __restrict__ pred,    // [B,NP,3]
    const float* __restrict__ exist,   // [B,NP]
    const float* __restrict__ cnt,     // [B,1]
    const float* __restrict__ gt,      // [B,NG,3]
    const int*   __restrict__ gcnt,    // [B]
    const float* __restrict__ weight,  // [1,NP]
    float* __restrict__ out)
{
    __shared__ float    sP[NP * 3];
    __shared__ float    sG[NG * 3];
    __shared__ unsigned aminkey[NG];
    __shared__ int      claimLds[NP];

    const int lane = threadIdx.x;      // 0..63
    const int l16  = lane & 15;
    const int grp  = lane >> 4;        // 0..3
    const int b    = blockIdx.x;
    const int cbase = l16 * 8;         // cols this lane builds (build phase)

    // ---- stage inputs ----
    for (int k = lane; k < NP * 3; k += 64) sP[k] = pred[b * NP * 3 + k];
    for (int k = lane; k < NG * 3; k += 64) sG[k] = gt[b * NG * 3 + k];
    claimLds[lane] = 0x7FFFFFFF; claimLds[lane + 64] = 0x7FFFFFFF;
    __syncthreads();

    // ---- per-row argmin (group g: rows 16g..16g+15; lane: 8 cols) ----
    {
        float px[8], py[8], pz[8];
        #pragma unroll
        for (int k = 0; k < 8; ++k) {
            const int c = cbase + k;
            px[k] = sP[c * 3 + 0]; py[k] = sP[c * 3 + 1]; pz[k] = sP[c * 3 + 2];
        }
        #pragma unroll 4
        for (int t = 0; t < 16; ++t) {
            const int row = grp * 16 + t;
            const float gx = sG[row * 3 + 0], gy = sG[row * 3 + 1], gz = sG[row * 3 + 2];
            unsigned km = 0xFFFFFFFFu;
            #pragma unroll
            for (int k = 0; k < 8; ++k) {
                const float d = dist3(px[k], py[k], pz[k], gx, gy, gz);
                const unsigned kb = (__float_as_uint(d) & 0xFFFFFF80u) | (unsigned)(cbase + k);
                km = umin32(km, kb);
            }
            km = dpp_min16(km);
            if (l16 == 0) aminkey[row] = km;
        }
    }
    __syncthreads();

    // ---- per-lane coord registers ----
    const float pax = sP[lane * 3 + 0], pay = sP[lane * 3 + 1], paz = sP[lane * 3 + 2];
    const float pbx = sP[(lane + 64) * 3 + 0], pby = sP[(lane + 64) * 3 + 1], pbz = sP[(lane + 64) * 3 + 2];
    const float gxr = sG[lane * 3 + 0], gyr = sG[lane * 3 + 1], gzr = sG[lane * 3 + 2]; // lane=row

    // ---- row reduction + greedy claim (lowest row wins each col) ----
    const unsigned mykey = aminkey[lane];                 // lane = row
    float u_row = __uint_as_float(mykey & 0xFFFFFF80u);   // u[i] <= row min (feasible)
    const int amincol = (int)(mykey & 127u);
    atomicMin(&claimLds[amincol], lane);
    __syncthreads();
    const int w0 = claimLds[lane];
    const int w1 = claimLds[lane + 64];
    int pc_a = (w0 < 64) ? w0 + 1 : 0;                    // col 'lane'    -> row+1 (0=free)
    int pc_b = (w1 < 64) ? w1 + 1 : 0;                    // col 'lane+64' -> row+1
    const int myclaim = claimLds[amincol];
    unsigned long long freemask = ~__ballot(myclaim == lane);  // unassigned rows

    float v_a = 0.0f, v_b = 0.0f;                         // col duals (lane=col)

    // ---- SAP for each free row ----
    while (freemask) {
        const int r0 = __ffsll(freemask) - 1;
        freemask &= freemask - 1;

        unsigned M_a = 0xFFFFFFFFu, M_b = 0xFFFFFFFFu;
        unsigned kill_a = 0u, kill_b = 0u;
        int      way_a = 255, way_b = 255;
        float    duse_a = 0.0f, duse_b = 0.0f;

        float enterD = 0.0f;
        bool  inp    = (lane == r0);
        float s1     = readlane_f(u_row, r0) - 1.0f;      // u[i0] - D - 1
        float gx     = readlane_f(gxr, r0);
        float gy     = readlane_f(gyr, r0);
        float gz     = readlane_f(gzr, r0);
        int   j0c    = 255;                               // root sentinel
        float Dend   = 0.0f;
        int   jb     = 0;

        for (int it = 0; it < 192; ++it) {
            // costs for pivot row, recomputed in-register
            const float c_a = dist3(pax, pay, paz, gx, gy, gz);
            const float c_b = dist3(pbx, pby, pbz, gx, gy, gz);

            // key = bits(redcost + D + 1) truncated | col, OR kill
            const float    bb_a = (c_a - v_a) - s1;
            const float    bb_b = (c_b - v_b) - s1;
            const unsigned kb_a = ((__float_as_uint(bb_a) & 0xFFFFFF80u) | (unsigned)lane) | kill_a;
            const unsigned kb_b = ((__float_as_uint(bb_b) & 0xFFFFFF80u) | (unsigned)(lane + 64)) | kill_b;
            if (kb_a < M_a) way_a = j0c;
            if (kb_b < M_b) way_b = j0c;
            M_a = umin32(M_a, kb_a);
            M_b = umin32(M_b, kb_b);

            const unsigned skey = wave_min64(umin32(M_a, M_b));
            const int   wc = (int)(skey & 127u);
            const float Dn = __uint_as_float(skey & 0xFFFFFF80u) - 1.0f;

            const int pw1 = __builtin_amdgcn_readlane(pc_a, wc & 63);
            const int pw2 = __builtin_amdgcn_readlane(pc_b, wc & 63);
            const int pw  = (wc < 64) ? pw1 : pw2;

            if (pw == 0 || it == 191) { jb = wc; Dend = Dn; break; }

            if (lane == pw - 1) { enterD = Dn; inp = true; }   // row enters SR path
            if (wc == lane)      { kill_a = 0xFFFFFFFFu; M_a = 0xFFFFFFFFu; duse_a = Dn; }
            if (wc == lane + 64) { kill_b = 0xFFFFFFFFu; M_b = 0xFFFFFFFFu; duse_b = Dn; }

            const int i0 = pw - 1;
            const float uw = readlane_f(u_row, i0);
            gx = readlane_f(gxr, i0);
            gy = readlane_f(gyr, i0);
            gz = readlane_f(gzr, i0);
            s1  = uw - Dn - 1.0f;
            j0c = wc;
        }

        // deferred dual updates: used cols v -= (Dend - duse); path rows u += (Dend - enterD)
        float da = Dend - duse_a, db = Dend - duse_b;
        v_a -= __uint_as_float(__float_as_uint(da) & kill_a);
        v_b -= __uint_as_float(__float_as_uint(db) & kill_b);
        u_row += inp ? (Dend - enterD) : 0.0f;

        // augment chase: p[j] <- p[way[j]]
        int j = jb;
        for (int g = 0; g < 192; ++g) {
            const int wj1 = __builtin_amdgcn_readlane(way_a, j & 63);
            const int wj2 = __builtin_amdgcn_readlane(way_b, j & 63);
            const int wj  = (j < 64) ? wj1 : wj2;
            int parp;
            if (wj == 255) parp = r0 + 1;
            else {
                const int q1 = __builtin_amdgcn_readlane(pc_a, wj & 63);
                const int q2 = __builtin_amdgcn_readlane(pc_b, wj & 63);
                parp = (wj < 64) ? q1 : q2;
            }
            if (j < 64) { if (lane == j)      pc_a = parp; }
            else        { if (lane == j - 64) pc_b = parp; }
            if (wj == 255) break;
            j = wj;
        }
    }

    // ---- losses (lane = col layout: pc_a/pc_b directly) ----
    const int pa = pc_a;
    const int pb = pc_b;
    float coord = 0.0f;
    const bool m_a = (pa != 0), m_b = (pb != 0);
    if (m_a) {
        const int g = pa - 1;
        for (int k = 0; k < 3; ++k) {
            const float d = fabsf(sP[lane * 3 + k] - sG[g * 3 + k]);
            coord += (d < 1.0f) ? 0.5f * d * d : (d - 0.5f);
        }
    }
    if (m_b) {
        const int g = pb - 1;
        for (int k = 0; k < 3; ++k) {
            const float d = fabsf(sP[(lane + 64) * 3 + k] - sG[g * 3 + k]);
            coord += (d < 1.0f) ? 0.5f * d * d : (d - 0.5f);
        }
    }
    float bce = 0.0f;
    {
        const float pe  = exist[b * NP + lane];
        const float lg  = fmaxf(logf(pe), -100.0f);
        const float l1m = fmaxf(log1pf(-pe), -100.0f);
        bce += -(m_a ? lg : l1m) * weight[lane];
    }
    {
        const float pe  = exist[b * NP + lane + 64];
        const float lg  = fmaxf(logf(pe), -100.0f);
        const float l1m = fmaxf(log1pf(-pe), -100.0f);
        bce += -(m_b ? lg : l1m) * weight[lane + 64];
    }

    double cs = (double)coord;
    double es = (double)bce;
    #pragma unroll
    for (int m = 1; m < 64; m <<= 1) {
        cs += __shfl_xor(cs, m);
        es += __shfl_xor(es, m);
    }

    if (lane == 0) {
        const float cp = cnt[b];
        const float dc = cp - (float)gcnt[b];
        const float sample = (float)(cs / (double)(NG * 3))
                           + (float)(es / (double)NP)
                           + dc * dc;
        atomicAdd(out, sample / (float)BATCH);
    }
}

extern "C" void kernel_launch(void* const* d_in, const int* in_sizes, int n_in,
                              void* d_out, int out_size, void* d_ws, size_t ws_size,
                              hipStream_t stream) {
    const float* pred   = (const float*)d_in[0];  // [32,128,3]
    const float* exist  = (const float*)d_in[1];  // [32,128]
    const float* cnt    = (const float*)d_in[2];  // [32,1]
    const float* gt     = (const float*)d_in[3];  // [32,64,3]
    const int*   gcnt   = (const int*)d_in[4];    // [32]
    const float* weight = (const float*)d_in[5];  // [1,128]
    float* out = (float*)d_out;

    hipMemsetAsync(out, 0, sizeof(float), stream);
    mtl_kernel<<<BATCH, 64, 0, stream>>>(pred, exist, cnt, gt, gcnt, weight, out);
}